// Round 14
// baseline (272.860 us; speedup 1.0000x reference)
//
#include <hip/hip_runtime.h>
#include <stdint.h>

// GroupedQueryLatentAttention on MI355X (gfx950).
// B=2 S=2048 HID=2048 HEADS=16 D=128 GROUPS=4 LATENT=512 KV=512.
// R14: big GEMMs re-tiled for perfect fill: BM=256 x BN=128 x BK=64, 8 waves
// (4M x 2N), 2-phase pipelined, grid (16,16)=256 blocks = 1/CU 100% fill.
// Fragment-packed LDS (96KB, linear ds_read, 0 conflicts). Counted vmcnt
// (4/1, never 0 mid-loop); per-wave stage queue [A x4, B-h0, B-h1].
// q/latent de-merged (N=2560 was unfillable); latent on 128^2 gemm_bt.
// attn (R11 softmax, stride 2048), mega_prep, kv GEMM, transpose_v as before.

#define DEV static __device__ __forceinline__

using short8 = __attribute__((ext_vector_type(8))) short;
using f32x4  = __attribute__((ext_vector_type(4))) float;

typedef __attribute__((address_space(1))) void gvoid;
typedef __attribute__((address_space(3))) void lvoid;

DEV unsigned short f2b(float f) {
  unsigned u = __builtin_bit_cast(unsigned, f);
  unsigned r = (u + 0x7fffu + ((u >> 16) & 1u)) >> 16;
  return (unsigned short)r;
}
DEV float b2f(unsigned short s) {
  unsigned u = ((unsigned)s) << 16;
  return __builtin_bit_cast(float, u);
}

DEV unsigned cvtpk(float lo, float hi) {
  unsigned r;
  asm("v_cvt_pk_bf16_f32 %0, %1, %2" : "=v"(r) : "v"(lo), "v"(hi));
  return r;
}

DEV float ex2(float x) { return __builtin_amdgcn_exp2f(x); }

// async global->LDS, 16B per lane. LDS dest resolves to firstlane base + lane*16.
DEV void async16(const void* g, void* l) {
  __builtin_amdgcn_global_load_lds((gvoid*)(uintptr_t)g,
                                   (lvoid*)(uint32_t)(uintptr_t)l, 16, 0, 0);
}

DEV f32x4 mfma16(short8 a, short8 b, f32x4 c) {
  return __builtin_amdgcn_mfma_f32_16x16x32_bf16(a, b, c, 0, 0, 0);
}

// ---------------- mega prep: cvt + all weight transposes + biases ----------
// bid: [0,4096) h->bf16 | [4096,8192) qscale*Wq^T | [8192,9216) Wl^T
// [9216,9472) Wk^T | [9472,9728) Wv^T | [9728,13824) Wo^T | 13824 biases
__global__ __launch_bounds__(256) void mega_prep(
    const float* __restrict__ h, unsigned short* __restrict__ hb,
    const float* __restrict__ Wq, const float* __restrict__ Wl,
    const float* __restrict__ Wk, const float* __restrict__ Wv,
    const float* __restrict__ Wo,
    unsigned short* __restrict__ WqT, unsigned short* __restrict__ WlT,
    unsigned short* __restrict__ WkvT, unsigned short* __restrict__ WoT,
    const float* __restrict__ bq,
    const float* __restrict__ bk, const float* __restrict__ bv,
    float* __restrict__ bqs, float* __restrict__ bkv, float qscale) {
  __shared__ float tile[32][33];
  const int bid = blockIdx.x;
  const int tid = threadIdx.x;

  if (bid < 4096) {
    long i = ((long)bid * 256 + tid) * 8;
    float4 a = *(const float4*)(h + i);
    float4 b = *(const float4*)(h + i + 4);
    short8 o;
    o[0] = (short)f2b(a.x); o[1] = (short)f2b(a.y);
    o[2] = (short)f2b(a.z); o[3] = (short)f2b(a.w);
    o[4] = (short)f2b(b.x); o[5] = (short)f2b(b.y);
    o[6] = (short)f2b(b.z); o[7] = (short)f2b(b.w);
    *(short8*)(hb + i) = o;
    return;
  }

  const float* in; unsigned short* out; int R, C, bx, by; float sc = 1.0f;
  if (bid < 8192) {
    int l = bid - 4096; in = Wq; out = WqT; R = 2048; C = 2048;
    bx = l & 63; by = l >> 6; sc = qscale;
  } else if (bid < 9216) {
    int l = bid - 8192; in = Wl; out = WlT; R = 2048; C = 512;
    bx = l & 15; by = l >> 4;
  } else if (bid < 9472) {
    int l = bid - 9216; in = Wk; out = WkvT; R = 512; C = 512;
    bx = l & 15; by = l >> 4;
  } else if (bid < 9728) {
    int l = bid - 9472; in = Wv; out = WkvT + 262144; R = 512; C = 512;
    bx = l & 15; by = l >> 4;
  } else if (bid < 13824) {
    int l = bid - 9728; in = Wo; out = WoT; R = 2048; C = 2048;
    bx = l & 63; by = l >> 6;
  } else {
    for (int t = tid; t < 2048; t += 256) bqs[t] = bq[t] * qscale;
    for (int t = tid; t < 1024; t += 256)
      bkv[t] = (t < 512) ? bk[t] : bv[t - 512];
    return;
  }

  int bc = bx * 32, br = by * 32;
  int tx = tid & 31, ty0 = tid >> 5;
#pragma unroll
  for (int ty = ty0; ty < 32; ty += 8)
    tile[ty][tx] = in[(size_t)(br + ty) * C + bc + tx] * sc;
  __syncthreads();
#pragma unroll
  for (int ty = ty0; ty < 32; ty += 8)
    out[(size_t)(bc + ty) * R + br + tx] = f2b(tile[tx][ty]);
}

// ---------------- V-part transpose ----------------
__global__ __launch_bounds__(256) void transpose_v(
    const unsigned short* __restrict__ in, unsigned short* __restrict__ out) {
  __shared__ float tile[32][33];
  int b = blockIdx.z;
  int bc = blockIdx.x * 32;
  int br = blockIdx.y * 32;
  const unsigned short* ip = in + (size_t)b * 2048 * 1024 + 512;
  unsigned short* op = out + (size_t)b * 512 * 2048;
  int tx = threadIdx.x & 31, ty0 = threadIdx.x >> 5;
#pragma unroll
  for (int ty = ty0; ty < 32; ty += 8)
    tile[ty][tx] = b2f(ip[(size_t)(br + ty) * 1024 + bc + tx]);
  __syncthreads();
#pragma unroll
  for (int ty = ty0; ty < 32; ty += 8)
    op[(size_t)(bc + ty) * 2048 + br + tx] = f2b(tile[tx][ty]);
}

// ---------------- GEMM 128x128 (latent + kv projections) ----------------
template <int OUT_F32>
__global__ __launch_bounds__(256) void gemm_bt(
    const unsigned short* __restrict__ A, const unsigned short* __restrict__ Bt,
    const float* __restrict__ bias, void* __restrict__ Cout,
    int M, int N, int K, int lda, float scale) {
  __shared__ unsigned short As[128 * 32];
  __shared__ unsigned short Bs[128 * 32];
  int tid = threadIdx.x;
  int lane = tid & 63, wave = tid >> 6;
  int wr = wave >> 1, wc = wave & 1;
  int lq = lane & 15, grp = lane >> 4;
  int brow = blockIdx.y * 128, bcol = blockIdx.x * 128;

  f32x4 acc[4][4] = {};

  for (int k0 = 0; k0 < K; k0 += 32) {
    {
      int e0 = tid * 8;
      int r0 = e0 >> 5, c0 = e0 & 31;
      async16(A + (size_t)(brow + r0) * lda + k0 + c0, As + e0);
      async16(Bt + (size_t)(bcol + r0) * K + k0 + c0, Bs + e0);
      int e1 = (256 + tid) * 8;
      int r1 = e1 >> 5, c1 = e1 & 31;
      async16(A + (size_t)(brow + r1) * lda + k0 + c1, As + e1);
      async16(Bt + (size_t)(bcol + r1) * K + k0 + c1, Bs + e1);
    }
    __syncthreads();

    short8 af[4], bf[4];
#pragma unroll
    for (int m = 0; m < 4; m++)
      af[m] = *(const short8*)(As + (wr * 64 + m * 16 + lq) * 32 + grp * 8);
#pragma unroll
    for (int n = 0; n < 4; n++)
      bf[n] = *(const short8*)(Bs + (wc * 64 + n * 16 + lq) * 32 + grp * 8);
#pragma unroll
    for (int m = 0; m < 4; m++)
#pragma unroll
      for (int n = 0; n < 4; n++)
        acc[m][n] = mfma16(af[m], bf[n], acc[m][n]);
    __syncthreads();
  }

#pragma unroll
  for (int n = 0; n < 4; n++) {
    int col = bcol + wc * 64 + n * 16 + lq;
    float bv = bias[col];
#pragma unroll
    for (int m = 0; m < 4; m++) {
#pragma unroll
      for (int r = 0; r < 4; r++) {
        int row = brow + wr * 64 + m * 16 + grp * 4 + r;
        float v = (acc[m][n][r] + bv) * scale;
        if (OUT_F32)
          ((float*)Cout)[(size_t)row * N + col] = v;
        else
          ((unsigned short*)Cout)[(size_t)row * N + col] = f2b(v);
      }
    }
  }
}

// ---------------- GEMM 256x128x64, 8 waves (4Mx2N), 2-phase pipelined ------
// LDS per buf: A 32 slots (1KB each: 16 rows x 32 K, lane-linear) + B 16
// slots = 48KB; 2 bufs = 96KB. A slot fa=(wr4ml)*2+kk: row (fa>>1)*16+lq,
// K (fa&1)*32+grp*8. B slot g=(wc*4+nl)*2+kk, same shape over C-cols.
// Per-wave stage queue per K-tile: [A x4 (p0), B-h0, B-h1 (p1)] where wave w
// stages A slots w*4..w*4+3, B-h0 slot ((w&3)|((w>>2)<<3)), B-h1 = +4.
// p0(T): read A(T)+B-h0(T), stage A(T+1), MFMA nl0-1; end vmcnt(4) [drains
// B-h1(T)]. p1(T): read B-h1(T), stage B(T+1), MFMA nl2-3; end vmcnt(1)
// [drains A(T+1)+B-h0(T+1), leaves B-h1(T+1) in flight]. Never 0 mid-loop.
template <int OUT_F32>
__global__ __launch_bounds__(512, 1) void gemm_2ph(
    const unsigned short* __restrict__ A, const unsigned short* __restrict__ Bt,
    const float* __restrict__ bias, void* __restrict__ Cout,
    int M, int N, int K, float scale) {
  __shared__ __align__(1024) unsigned short L[2][24576];  // 2 x 48KB
  const int tid = threadIdx.x, lane = tid & 63, wave = tid >> 6;
  const int lq = lane & 15, grp = lane >> 4;
  const int wr = wave >> 1, wc = wave & 1;

  // XCD-aware bijective remap (nwg = 256, %8==0)
  const int gx = gridDim.x;
  int nwg = gx * gridDim.y;
  int bid = blockIdx.y * gx + blockIdx.x;
  int wgid = (bid & 7) * (nwg >> 3) + (bid >> 3);
  int bx = wgid % gx, by = wgid / gx;
  const int brow = by * 256, bcol = bx * 128;

  // staging pointers: A slots fa = wave*4+j; B slots h0 and h1
  const unsigned short* srcA[4];
  unsigned short* dstA[4];
#pragma unroll
  for (int j = 0; j < 4; j++) {
    int fa = wave * 4 + j;
    srcA[j] = A + (size_t)(brow + (fa >> 1) * 16 + lq) * K + (fa & 1) * 32 + grp * 8;
    dstA[j] = &L[0][0] + fa * 512 + lane * 8;
  }
  const int g0 = (wave & 3) | ((wave >> 2) << 3), g1 = g0 + 4;
  const unsigned short* srcB0 =
      Bt + (size_t)(bcol + (g0 >> 1) * 16 + lq) * K + (g0 & 1) * 32 + grp * 8;
  const unsigned short* srcB1 =
      Bt + (size_t)(bcol + (g1 >> 1) * 16 + lq) * K + (g1 & 1) * 32 + grp * 8;
  unsigned short* dstB0 = &L[0][0] + 16384 + g0 * 512 + lane * 8;
  unsigned short* dstB1 = &L[0][0] + 16384 + g1 * 512 + lane * 8;

  auto stgA = [&](int p, int k0) {
#pragma unroll
    for (int j = 0; j < 4; j++) async16(srcA[j] + k0, dstA[j] + p * 24576);
  };
  auto stgB = [&](int p, int k0) {
    async16(srcB0 + k0, dstB0 + p * 24576);
    async16(srcB1 + k0, dstB1 + p * 24576);
  };
  auto ldAf = [&](int p, int ml, int kk) -> short8 {
    return *(const short8*)(&L[p][((wr * 4 + ml) * 2 + kk) * 512 + lane * 8]);
  };
  auto ldBf = [&](int p, int nl, int kk) -> short8 {
    return *(const short8*)(&L[p][16384 + ((wc * 4 + nl) * 2 + kk) * 512 + lane * 8]);
  };

  f32x4 acc[4][4] = {};
  short8 af[4][2], bf[2][2];
  const int NT = K >> 6;

  // prologue: tile 0 -> buf 0; per-wave queue [A x4, h0, h1]
  stgA(0, 0); stgB(0, 0);
  asm volatile("s_waitcnt vmcnt(1)" ::: "memory");  // A + h0 landed
  __builtin_amdgcn_s_barrier();

  for (int T = 0; T < NT; ++T) {
    const int cur = T & 1, nxt = cur ^ 1;
    const bool pf = (T + 1 < NT);
    const int k1 = (T + 1) << 6;

    // ---- p0: read A + B-h0, stage A(T+1), MFMA nl 0,1 ----
#pragma unroll
    for (int ml = 0; ml < 4; ml++) {
      af[ml][0] = ldAf(cur, ml, 0);
      af[ml][1] = ldAf(cur, ml, 1);
    }
#pragma unroll
    for (int nl = 0; nl < 2; nl++) {
      bf[nl][0] = ldBf(cur, nl, 0);
      bf[nl][1] = ldBf(cur, nl, 1);
    }
    if (pf) stgA(nxt, k1);
    __builtin_amdgcn_s_setprio(1);
#pragma unroll
    for (int ml = 0; ml < 4; ml++)
#pragma unroll
      for (int nl = 0; nl < 2; nl++) {
        acc[ml][nl] = mfma16(af[ml][0], bf[nl][0], acc[ml][nl]);
        acc[ml][nl] = mfma16(af[ml][1], bf[nl][1], acc[ml][nl]);
      }
    __builtin_amdgcn_s_setprio(0);
    if (pf) asm volatile("s_waitcnt vmcnt(4)" ::: "memory");  // B-h1(T) landed
    else    asm volatile("s_waitcnt vmcnt(0)" ::: "memory");
    __builtin_amdgcn_s_barrier();

    // ---- p1: read B-h1, stage B(T+1), MFMA nl 2,3 ----
#pragma unroll
    for (int nl = 0; nl < 2; nl++) {
      bf[nl][0] = ldBf(cur, 2 + nl, 0);
      bf[nl][1] = ldBf(cur, 2 + nl, 1);
    }
    if (pf) stgB(nxt, k1);
    __builtin_amdgcn_s_setprio(1);
#pragma unroll
    for (int ml = 0; ml < 4; ml++)
#pragma unroll
      for (int nl = 0; nl < 2; nl++) {
        acc[ml][2 + nl] = mfma16(af[ml][0], bf[nl][0], acc[ml][2 + nl]);
        acc[ml][2 + nl] = mfma16(af[ml][1], bf[nl][1], acc[ml][2 + nl]);
      }
    __builtin_amdgcn_s_setprio(0);
    if (pf) asm volatile("s_waitcnt vmcnt(1)" ::: "memory");  // A+h0(T+1) landed
    __builtin_amdgcn_s_barrier();
  }

  // ---- epilogue: row = brow + wr*64 + ml*16 + grp*4 + r, col = bcol + wc*64 + nl*16 + lq
#pragma unroll
  for (int nl = 0; nl < 4; nl++) {
    int col = bcol + wc * 64 + nl * 16 + lq;
    float bv = bias[col];
#pragma unroll
    for (int ml = 0; ml < 4; ml++) {
#pragma unroll
      for (int r = 0; r < 4; r++) {
        int row = brow + wr * 64 + ml * 16 + grp * 4 + r;
        float v = (acc[ml][nl][r] + bv) * scale;
        if (OUT_F32)
          ((float*)Cout)[(size_t)row * N + col] = v;
        else
          ((unsigned short*)Cout)[(size_t)row * N + col] = f2b(v);
      }
    }
  }
}

// ---------------- flash attention (R11, q row stride 2048) ----------------
__global__ __launch_bounds__(256, 2) void attn_kernel(
    const unsigned short* __restrict__ q,   // [B*S][2048], pre-scaled
    const unsigned short* __restrict__ kv,  // [B*S][1024]; K = cols 0..511
    const unsigned short* __restrict__ vt,  // [(b*4+g)*128 + d][2048]
    unsigned short* __restrict__ ctx) {     // [B*S][2048]
  __shared__ unsigned short KV[2][32][512];
  const int lane = threadIdx.x & 63, wave = threadIdx.x >> 6;
  const int lq = lane & 15, grp = lane >> 4;
  const int bid = blockIdx.x;
  const int combo = bid & 7;
  const int slot = bid >> 3;
  const int b = combo >> 2, g = combo & 3;
  const int h = g * 4 + (slot >> 4);
  const int qbase = (slot & 15) * 128 + wave * 32;

  short8 qf[2][4];
#pragma unroll
  for (int qs = 0; qs < 2; qs++) {
    const unsigned short* qp =
        q + ((size_t)(b * 2048 + qbase + qs * 16 + lq)) * 2048 + h * 128 + grp * 8;
#pragma unroll
    for (int c = 0; c < 4; c++) qf[qs][c] = *(const short8*)(qp + c * 32);
  }

  f32x4 o[2][8] = {};
  float lsum[2] = {0.f, 0.f};
  const float C = 20.0f;

  const int kvperm = (lq >> 2) * 8 + (lq & 3);
  const unsigned short* kB = kv + (size_t)b * 2048 * 1024 + g * 128 + grp * 8;
  const unsigned short* vB =
      vt + ((size_t)((b * 4 + g) * 128 + lq)) * 2048 + grp * 8;
  const int fbase = wave * 8;
  unsigned short* dstb = &KV[0][fbase][0] + lane * 8;

  auto stage = [&](int bn, int kv0) {
    unsigned short* dst = dstb + bn * 16384;
    if (fbase < 16) {
#pragma unroll
      for (int j = 0; j < 8; j++) {
        int f = fbase + j, t = f >> 2, c = f & 3;
        const unsigned short* src =
            kB + (size_t)(kv0 + (t >> 1) * 32 + (t & 1) * 4 + kvperm) * 1024 + c * 32;
        async16(src, dst + j * 512);
      }
    } else {
#pragma unroll
      for (int j = 0; j < 8; j++) {
        int f = fbase - 16 + j, d0 = f >> 1, u = f & 1;
        const unsigned short* src = vB + (size_t)(d0 * 16) * 2048 + kv0 + u * 32;
        async16(src, dst + j * 512);
      }
    }
  };

  stage(0, 0);
  int buf = 0;
  for (int it = 0; it < 32; ++it) {
    __syncthreads();
    if (it < 31) stage(buf ^ 1, (it + 1) * 64);
    const unsigned short* Kb = &KV[buf][0][0] + lane * 8;

    f32x4 s[2][4] = {};
    __builtin_amdgcn_s_setprio(1);
#pragma unroll
    for (int c = 0; c < 4; c++) {
      short8 kf0 = *(const short8*)(Kb + (0 + c) * 512);
      short8 kf1 = *(const short8*)(Kb + (4 + c) * 512);
      short8 kf2 = *(const short8*)(Kb + (8 + c) * 512);
      short8 kf3 = *(const short8*)(Kb + (12 + c) * 512);
#pragma unroll
      for (int qs = 0; qs < 2; qs++) {
        s[qs][0] = mfma16(kf0, qf[qs][c], s[qs][0]);
        s[qs][1] = mfma16(kf1, qf[qs][c], s[qs][1]);
        s[qs][2] = mfma16(kf2, qf[qs][c], s[qs][2]);
        s[qs][3] = mfma16(kf3, qf[qs][c], s[qs][3]);
      }
    }
    __builtin_amdgcn_s_setprio(0);

    short8 pf[2][2];
#pragma unroll
    for (int qs = 0; qs < 2; qs++) {
      float ps = 0.f;
      union { short8 v; unsigned w[4]; } pk0, pk1;
#pragma unroll
      for (int t = 0; t < 4; t++) {
        float e0 = ex2(s[qs][t][0] - C);
        float e1 = ex2(s[qs][t][1] - C);
        float e2 = ex2(s[qs][t][2] - C);
        float e3 = ex2(s[qs][t][3] - C);
        ps += (e0 + e1) + (e2 + e3);
        unsigned w0 = cvtpk(e0, e1), w1 = cvtpk(e2, e3);
        if (t == 0) { pk0.w[0] = w0; pk0.w[1] = w1; }
        else if (t == 1) { pk0.w[2] = w0; pk0.w[3] = w1; }
        else if (t == 2) { pk1.w[0] = w0; pk1.w[1] = w1; }
        else { pk1.w[2] = w0; pk1.w[3] = w1; }
      }
      lsum[qs] += ps;
      pf[qs][0] = pk0.v;
      pf[qs][1] = pk1.v;
    }

    const unsigned short* Vb = Kb + 16 * 512;
    __builtin_amdgcn_s_setprio(1);
#pragma unroll
    for (int d0 = 0; d0 < 8; d0++) {
      short8 v0 = *(const short8*)(Vb + (d0 * 2 + 0) * 512);
      short8 v1 = *(const short8*)(Vb + (d0 * 2 + 1) * 512);
#pragma unroll
      for (int qs = 0; qs < 2; qs++) {
        o[qs][d0] = mfma16(pf[qs][0], v0, o[qs][d0]);
        o[qs][d0] = mfma16(pf[qs][1], v1, o[qs][d0]);
      }
    }
    __builtin_amdgcn_s_setprio(0);
    buf ^= 1;
  }

  unsigned short* cp = ctx + ((size_t)(b * 2048 + qbase)) * 2048 + h * 128;
#pragma unroll
  for (int qs = 0; qs < 2; qs++) {
    float l = lsum[qs];
    l += __shfl_xor(l, 16);
    l += __shfl_xor(l, 32);
    float ri = 1.0f / l;
    float r0 = __shfl(ri, grp * 4 + 0), r1 = __shfl(ri, grp * 4 + 1);
    float r2 = __shfl(ri, grp * 4 + 2), r3 = __shfl(ri, grp * 4 + 3);
#pragma unroll
    for (int d0 = 0; d0 < 8; d0++) {
      int col = d0 * 16 + lq;
      cp[(size_t)(qs * 16 + grp * 4 + 0) * 2048 + col] = f2b(o[qs][d0][0] * r0);
      cp[(size_t)(qs * 16 + grp * 4 + 1) * 2048 + col] = f2b(o[qs][d0][1] * r1);
      cp[(size_t)(qs * 16 + grp * 4 + 2) * 2048 + col] = f2b(o[qs][d0][2] * r2);
      cp[(size_t)(qs * 16 + grp * 4 + 3) * 2048 + col] = f2b(o[qs][d0][3] * r3);
    }
  }
}

// ---------------- host ----------------
extern "C" void kernel_launch(void* const* d_in, const int* in_sizes, int n_in,
                              void* d_out, int out_size, void* d_ws, size_t ws_size,
                              hipStream_t stream) {
  const float* h  = (const float*)d_in[0];
  const float* Wq = (const float*)d_in[1];
  const float* bq = (const float*)d_in[2];
  const float* Wl = (const float*)d_in[3];
  const float* bl = (const float*)d_in[4];
  const float* Wk = (const float*)d_in[5];
  const float* bk = (const float*)d_in[6];
  const float* Wv = (const float*)d_in[7];
  const float* bv = (const float*)d_in[8];
  const float* Wo = (const float*)d_in[9];
  const float* bo = (const float*)d_in[10];
  float* out = (float*)d_out;

  const int M = 4096;  // B*S

  char* w = (char*)d_ws;
  auto take = [&](size_t elems) {  // elems are ushort-sized units
    void* p = (void*)w;
    w += (elems * 2 + 255) & ~(size_t)255;
    return (unsigned short*)p;
  };
  unsigned short* hb   = take(8388608);  // [4096][2048]
  unsigned short* WqT  = take(4194304);  // [2048][2048] (scale folded)
  unsigned short* WlT  = take(1048576);  // [512][2048]
  unsigned short* WkvT = take(524288);   // [1024][512]
  unsigned short* WoT  = take(4194304);  // [2048][2048]
  unsigned short* qb   = take(8388608);  // [4096][2048]
  unsigned short* lat  = take(2097152);  // [4096][512]
  unsigned short* kvb  = take(4194304);  // [4096][1024]
  unsigned short* vtb  = take(2097152);  // [2*512][2048]
  unsigned short* ctx  = take(8388608);  // [4096][2048]
  float* bqs = (float*)take(4096);       // 2048 f32
  float* bkv = (float*)take(2048);       // 1024 f32

  // q scale = 1/sqrt(128) * log2(e), folded into Wq/bq during prep
  const float scale = 0.08838834764831845f * 1.4426950408889634f;

  mega_prep<<<13825, 256, 0, stream>>>(h, hb, Wq, Wl, Wk, Wv, Wo,
                                       WqT, WlT, WkvT, WoT,
                                       bq, bk, bv, bqs, bkv, scale);

  gemm_2ph<0><<<dim3(16, 16), 512, 0, stream>>>(hb, WqT, bqs, qb, M, 2048, 2048, 1.0f);
  gemm_bt<0><<<dim3(4, 32), 256, 0, stream>>>(hb, WlT, bl, lat, M, 512, 2048, 2048, 1.0f);
  gemm_bt<0><<<dim3(8, 32), 256, 0, stream>>>(lat, WkvT, bkv, kvb, M, 1024, 512, 512, 1.0f);

  transpose_v<<<dim3(16, 64, 2), 256, 0, stream>>>(kvb, vtb);

  attn_kernel<<<512, 256, 0, stream>>>(qb, kvb, vtb, ctx);

  gemm_2ph<1><<<dim3(16, 16), 512, 0, stream>>>(ctx, WoT, bo, out, M, 2048, 2048, 1.0f);
}

// Round 15
// 241.332 us; speedup vs baseline: 1.1306x; 1.1306x over previous
//
#include <hip/hip_runtime.h>
#include <stdint.h>

// GroupedQueryLatentAttention on MI355X (gfx950).
// B=2 S=2048 HID=2048 HEADS=16 D=128 GROUPS=4 LATENT=512 KV=512.
// R15 = R13 verbatim (proven best, 241.8 us). R14's 2-phase 256x128 retile
// regressed (-31 us: tile reuse > grid fill); reverted.
// Pipeline: mega_prep (cvt+transposes+bias, 1 launch) -> gemm_8ph q+latent
// merged (256x256x64, 4-phase, frag-packed LDS, counted vmcnt, XCD swizzle)
// -> gemm_bt kv -> transpose_v -> attn (KVBLK=64, fixed-offset exp2 softmax,
// cvt_pk, XCD-pinned KV) -> gemm_8ph o-proj.

#define DEV static __device__ __forceinline__

using short8 = __attribute__((ext_vector_type(8))) short;
using f32x4  = __attribute__((ext_vector_type(4))) float;

typedef __attribute__((address_space(1))) void gvoid;
typedef __attribute__((address_space(3))) void lvoid;

DEV unsigned short f2b(float f) {
  unsigned u = __builtin_bit_cast(unsigned, f);
  unsigned r = (u + 0x7fffu + ((u >> 16) & 1u)) >> 16;
  return (unsigned short)r;
}
DEV float b2f(unsigned short s) {
  unsigned u = ((unsigned)s) << 16;
  return __builtin_bit_cast(float, u);
}

DEV unsigned cvtpk(float lo, float hi) {
  unsigned r;
  asm("v_cvt_pk_bf16_f32 %0, %1, %2" : "=v"(r) : "v"(lo), "v"(hi));
  return r;
}

DEV float ex2(float x) { return __builtin_amdgcn_exp2f(x); }

// async global->LDS, 16B per lane. LDS dest resolves to firstlane base + lane*16.
DEV void async16(const void* g, void* l) {
  __builtin_amdgcn_global_load_lds((gvoid*)(uintptr_t)g,
                                   (lvoid*)(uint32_t)(uintptr_t)l, 16, 0, 0);
}

DEV f32x4 mfma16(short8 a, short8 b, f32x4 c) {
  return __builtin_amdgcn_mfma_f32_16x16x32_bf16(a, b, c, 0, 0, 0);
}

// ---------------- mega prep: cvt + all weight transposes + bias concat -----
__global__ __launch_bounds__(256) void mega_prep(
    const float* __restrict__ h, unsigned short* __restrict__ hb,
    const float* __restrict__ Wq, const float* __restrict__ Wl,
    const float* __restrict__ Wk, const float* __restrict__ Wv,
    const float* __restrict__ Wo,
    unsigned short* __restrict__ WqlT, unsigned short* __restrict__ WkvT,
    unsigned short* __restrict__ WoT,
    const float* __restrict__ bq, const float* __restrict__ bl,
    const float* __restrict__ bk, const float* __restrict__ bv,
    float* __restrict__ bql, float* __restrict__ bkv, float qscale) {
  __shared__ float tile[32][33];
  const int bid = blockIdx.x;
  const int tid = threadIdx.x;

  if (bid < 4096) {
    long i = ((long)bid * 256 + tid) * 8;
    float4 a = *(const float4*)(h + i);
    float4 b = *(const float4*)(h + i + 4);
    short8 o;
    o[0] = (short)f2b(a.x); o[1] = (short)f2b(a.y);
    o[2] = (short)f2b(a.z); o[3] = (short)f2b(a.w);
    o[4] = (short)f2b(b.x); o[5] = (short)f2b(b.y);
    o[6] = (short)f2b(b.z); o[7] = (short)f2b(b.w);
    *(short8*)(hb + i) = o;
    return;
  }

  const float* in; unsigned short* out; int R, C, bx, by; float sc = 1.0f;
  if (bid < 8192) {
    int l = bid - 4096; in = Wq; out = WqlT; R = 2048; C = 2048;
    bx = l & 63; by = l >> 6; sc = qscale;
  } else if (bid < 9216) {
    int l = bid - 8192; in = Wl; out = WqlT + 2048 * 2048; R = 2048; C = 512;
    bx = l & 15; by = l >> 4;
  } else if (bid < 9472) {
    int l = bid - 9216; in = Wk; out = WkvT; R = 512; C = 512;
    bx = l & 15; by = l >> 4;
  } else if (bid < 9728) {
    int l = bid - 9472; in = Wv; out = WkvT + 262144; R = 512; C = 512;
    bx = l & 15; by = l >> 4;
  } else if (bid < 13824) {
    int l = bid - 9728; in = Wo; out = WoT; R = 2048; C = 2048;
    bx = l & 63; by = l >> 6;
  } else {
    for (int t = tid; t < 2560; t += 256)
      bql[t] = (t < 2048) ? bq[t] * qscale : bl[t - 2048];
    for (int t = tid; t < 1024; t += 256)
      bkv[t] = (t < 512) ? bk[t] : bv[t - 512];
    return;
  }

  int bc = bx * 32, br = by * 32;
  int tx = tid & 31, ty0 = tid >> 5;
#pragma unroll
  for (int ty = ty0; ty < 32; ty += 8)
    tile[ty][tx] = in[(size_t)(br + ty) * C + bc + tx] * sc;
  __syncthreads();
#pragma unroll
  for (int ty = ty0; ty < 32; ty += 8)
    out[(size_t)(bc + ty) * R + br + tx] = f2b(tile[tx][ty]);
}

// ---------------- V-part transpose ----------------
__global__ __launch_bounds__(256) void transpose_v(
    const unsigned short* __restrict__ in, unsigned short* __restrict__ out) {
  __shared__ float tile[32][33];
  int b = blockIdx.z;
  int bc = blockIdx.x * 32;
  int br = blockIdx.y * 32;
  const unsigned short* ip = in + (size_t)b * 2048 * 1024 + 512;
  unsigned short* op = out + (size_t)b * 512 * 2048;
  int tx = threadIdx.x & 31, ty0 = threadIdx.x >> 5;
#pragma unroll
  for (int ty = ty0; ty < 32; ty += 8)
    tile[ty][tx] = b2f(ip[(size_t)(br + ty) * 1024 + bc + tx]);
  __syncthreads();
#pragma unroll
  for (int ty = ty0; ty < 32; ty += 8)
    op[(size_t)(bc + ty) * 2048 + br + tx] = f2b(tile[tx][ty]);
}

// ---------------- GEMM 128x128 (kv projection) ----------------
template <int OUT_F32>
__global__ __launch_bounds__(256) void gemm_bt(
    const unsigned short* __restrict__ A, const unsigned short* __restrict__ Bt,
    const float* __restrict__ bias, void* __restrict__ Cout,
    int M, int N, int K, int lda, float scale) {
  __shared__ unsigned short As[128 * 32];
  __shared__ unsigned short Bs[128 * 32];
  int tid = threadIdx.x;
  int lane = tid & 63, wave = tid >> 6;
  int wr = wave >> 1, wc = wave & 1;
  int lq = lane & 15, grp = lane >> 4;
  int brow = blockIdx.y * 128, bcol = blockIdx.x * 128;

  f32x4 acc[4][4] = {};

  for (int k0 = 0; k0 < K; k0 += 32) {
    {
      int e0 = tid * 8;
      int r0 = e0 >> 5, c0 = e0 & 31;
      async16(A + (size_t)(brow + r0) * lda + k0 + c0, As + e0);
      async16(Bt + (size_t)(bcol + r0) * K + k0 + c0, Bs + e0);
      int e1 = (256 + tid) * 8;
      int r1 = e1 >> 5, c1 = e1 & 31;
      async16(A + (size_t)(brow + r1) * lda + k0 + c1, As + e1);
      async16(Bt + (size_t)(bcol + r1) * K + k0 + c1, Bs + e1);
    }
    __syncthreads();

    short8 af[4], bf[4];
#pragma unroll
    for (int m = 0; m < 4; m++)
      af[m] = *(const short8*)(As + (wr * 64 + m * 16 + lq) * 32 + grp * 8);
#pragma unroll
    for (int n = 0; n < 4; n++)
      bf[n] = *(const short8*)(Bs + (wc * 64 + n * 16 + lq) * 32 + grp * 8);
#pragma unroll
    for (int m = 0; m < 4; m++)
#pragma unroll
      for (int n = 0; n < 4; n++)
        acc[m][n] = mfma16(af[m], bf[n], acc[m][n]);
    __syncthreads();
  }

#pragma unroll
  for (int n = 0; n < 4; n++) {
    int col = bcol + wc * 64 + n * 16 + lq;
    float bv = bias[col];
#pragma unroll
    for (int m = 0; m < 4; m++) {
#pragma unroll
      for (int r = 0; r < 4; r++) {
        int row = brow + wr * 64 + m * 16 + grp * 4 + r;
        float v = (acc[m][n][r] + bv) * scale;
        if (OUT_F32)
          ((float*)Cout)[(size_t)row * N + col] = v;
        else
          ((unsigned short*)Cout)[(size_t)row * N + col] = f2b(v);
      }
    }
  }
}

// ---------------- GEMM 256x256x64, 8 waves, 4-phase pipelined --------------
template <int OUT_F32>
__global__ __launch_bounds__(512, 1) void gemm_8ph(
    const unsigned short* __restrict__ A, const unsigned short* __restrict__ Bt,
    const float* __restrict__ bias, void* __restrict__ Cout,
    int M, int N, int K, float scale) {
  __shared__ __align__(1024) unsigned short L[2][32768];  // 2 x 64KB
  const int tid = threadIdx.x, lane = tid & 63, wave = tid >> 6;
  const int lq = lane & 15, grp = lane >> 4;
  const int wr = wave >> 2, wc = wave & 3;

  const int gx = gridDim.x;
  int nwg = gx * gridDim.y;
  int bid = blockIdx.y * gx + blockIdx.x;
  int wgid = (bid & 7) * (nwg >> 3) + (bid >> 3);
  int bx = wgid % gx, by = wgid / gx;
  const int brow = by * 256, bcol = bx * 256;

  const unsigned short* srcA[2];
  const unsigned short* srcB[2];
  unsigned short* dstA[2];
  unsigned short* dstB[2];
#pragma unroll
  for (int j = 0; j < 2; j++) {
    int f = wave + j * 8, kk = f & 1, fi = f >> 1;
    int awr = fi >> 2, aml = fi & 3;
    srcA[j] = A + (size_t)(brow + (awr * 8 + aml) * 16 + lq) * K + kk * 32 + grp * 8;
    dstA[j] = &L[0][0] + f * 512 + lane * 8;
    int bwc = fi >> 1, bnl = fi & 1;
    srcB[j] = Bt + (size_t)(bcol + (bwc * 4 + bnl) * 16 + lq) * K + kk * 32 + grp * 8;
    dstB[j] = &L[0][0] + 16384 + f * 512 + lane * 8;
  }
  auto stgA = [&](int p, int mh, int k0) {
#pragma unroll
    for (int j = 0; j < 2; j++)
      async16(srcA[j] + (size_t)mh * 64 * K + k0, dstA[j] + p * 32768 + mh * 8192);
  };
  auto stgB = [&](int p, int nh, int k0) {
#pragma unroll
    for (int j = 0; j < 2; j++)
      async16(srcB[j] + (size_t)nh * 32 * K + k0, dstB[j] + p * 32768 + nh * 8192);
  };
  auto ldAf = [&](int p, int mh, int ml, int kk) -> short8 {
    return *(const short8*)(&L[0][0] + p * 32768 + mh * 8192 +
                            ((wr * 4 + ml) * 2 + kk) * 512 + lane * 8);
  };
  auto ldBf = [&](int p, int nh, int nl, int kk) -> short8 {
    return *(const short8*)(&L[0][0] + p * 32768 + 16384 + nh * 8192 +
                            ((wc * 2 + nl) * 2 + kk) * 512 + lane * 8);
  };

  f32x4 acc[8][4] = {};
  short8 af[4][2], bf0[2][2], bf1[2][2];
  const int NT = K >> 6;

  stgA(0, 0, 0); stgB(0, 0, 0); stgB(0, 1, 0); stgA(0, 1, 0);
  asm volatile("s_waitcnt vmcnt(4)" ::: "memory");  // AH0,BH0 landed
  __builtin_amdgcn_s_barrier();

  for (int T = 0; T < NT; ++T) {
    const int cur = T & 1, nxt = cur ^ 1;
    const bool pf = (T + 1 < NT);
    const int k1 = (T + 1) << 6;

    // ---- q0: AH0+BH0 reads, stage AH0(T+1), acc[0..3][0..1] ----
#pragma unroll
    for (int ml = 0; ml < 4; ml++) {
      af[ml][0] = ldAf(cur, 0, ml, 0);
      af[ml][1] = ldAf(cur, 0, ml, 1);
    }
#pragma unroll
    for (int nl = 0; nl < 2; nl++) {
      bf0[nl][0] = ldBf(cur, 0, nl, 0);
      bf0[nl][1] = ldBf(cur, 0, nl, 1);
    }
    if (pf) stgA(nxt, 0, k1);
    __builtin_amdgcn_s_setprio(1);
#pragma unroll
    for (int ml = 0; ml < 4; ml++)
#pragma unroll
      for (int nl = 0; nl < 2; nl++) {
        acc[ml][nl] = mfma16(af[ml][0], bf0[nl][0], acc[ml][nl]);
        acc[ml][nl] = mfma16(af[ml][1], bf0[nl][1], acc[ml][nl]);
      }
    __builtin_amdgcn_s_setprio(0);
    if (pf) asm volatile("s_waitcnt vmcnt(4)" ::: "memory");  // BH1(T) landed
    else    asm volatile("s_waitcnt vmcnt(2)" ::: "memory");
    __builtin_amdgcn_s_barrier();

    // ---- q1: BH1 reads, stage BH0(T+1), acc[0..3][2..3] ----
#pragma unroll
    for (int nl = 0; nl < 2; nl++) {
      bf1[nl][0] = ldBf(cur, 1, nl, 0);
      bf1[nl][1] = ldBf(cur, 1, nl, 1);
    }
    if (pf) stgB(nxt, 0, k1);
    __builtin_amdgcn_s_setprio(1);
#pragma unroll
    for (int ml = 0; ml < 4; ml++)
#pragma unroll
      for (int nl = 0; nl < 2; nl++) {
        acc[ml][2 + nl] = mfma16(af[ml][0], bf1[nl][0], acc[ml][2 + nl]);
        acc[ml][2 + nl] = mfma16(af[ml][1], bf1[nl][1], acc[ml][2 + nl]);
      }
    __builtin_amdgcn_s_setprio(0);
    if (pf) asm volatile("s_waitcnt vmcnt(4)" ::: "memory");  // AH1(T) landed
    else    asm volatile("s_waitcnt vmcnt(0)" ::: "memory");
    __builtin_amdgcn_s_barrier();

    // ---- q2: AH1 reads, stage BH1(T+1), acc[4..7][0..1] ----
#pragma unroll
    for (int ml = 0; ml < 4; ml++) {
      af[ml][0] = ldAf(cur, 1, ml, 0);
      af[ml][1] = ldAf(cur, 1, ml, 1);
    }
    if (pf) stgB(nxt, 1, k1);
    __builtin_amdgcn_s_setprio(1);
#pragma unroll
    for (int ml = 0; ml < 4; ml++)
#pragma unroll
      for (int nl = 0; nl < 2; nl++) {
        acc[4 + ml][nl] = mfma16(af[ml][0], bf0[nl][0], acc[4 + ml][nl]);
        acc[4 + ml][nl] = mfma16(af[ml][1], bf0[nl][1], acc[4 + ml][nl]);
      }
    __builtin_amdgcn_s_setprio(0);
    __builtin_amdgcn_s_barrier();  // q3 reads nothing from LDS

    // ---- q3: stage AH1(T+1), acc[4..7][2..3] ----
    if (pf) stgA(nxt, 1, k1);
    __builtin_amdgcn_s_setprio(1);
#pragma unroll
    for (int ml = 0; ml < 4; ml++)
#pragma unroll
      for (int nl = 0; nl < 2; nl++) {
        acc[4 + ml][2 + nl] = mfma16(af[ml][0], bf1[nl][0], acc[4 + ml][2 + nl]);
        acc[4 + ml][2 + nl] = mfma16(af[ml][1], bf1[nl][1], acc[4 + ml][2 + nl]);
      }
    __builtin_amdgcn_s_setprio(0);
    if (pf) asm volatile("s_waitcnt vmcnt(4)" ::: "memory");  // AH0,BH0(T+1) landed
    __builtin_amdgcn_s_barrier();
  }

#pragma unroll
  for (int mh = 0; mh < 2; mh++)
#pragma unroll
    for (int ml = 0; ml < 4; ml++)
#pragma unroll
      for (int nh = 0; nh < 2; nh++)
#pragma unroll
        for (int nl = 0; nl < 2; nl++) {
          int col = bcol + wc * 64 + (nh * 2 + nl) * 16 + lq;
          float bv = bias[col];
          f32x4 a = acc[mh * 4 + ml][nh * 2 + nl];
#pragma unroll
          for (int r = 0; r < 4; r++) {
            int row = brow + wr * 128 + (mh * 4 + ml) * 16 + grp * 4 + r;
            float v = (a[r] + bv) * scale;
            if (OUT_F32)
              ((float*)Cout)[(size_t)row * N + col] = v;
            else
              ((unsigned short*)Cout)[(size_t)row * N + col] = f2b(v);
          }
        }
}

// ---------------- flash attention (R11, q row stride 2560) ----------------
__global__ __launch_bounds__(256, 2) void attn_kernel(
    const unsigned short* __restrict__ q,   // qlat [B*S][2560], cols 0..2047 = q
    const unsigned short* __restrict__ kv,  // [B*S][1024]; K = cols 0..511
    const unsigned short* __restrict__ vt,  // [(b*4+g)*128 + d][2048]
    unsigned short* __restrict__ ctx) {     // [B*S][2048]
  __shared__ unsigned short KV[2][32][512];
  const int lane = threadIdx.x & 63, wave = threadIdx.x >> 6;
  const int lq = lane & 15, grp = lane >> 4;
  const int bid = blockIdx.x;
  const int combo = bid & 7;
  const int slot = bid >> 3;
  const int b = combo >> 2, g = combo & 3;
  const int h = g * 4 + (slot >> 4);
  const int qbase = (slot & 15) * 128 + wave * 32;

  short8 qf[2][4];
#pragma unroll
  for (int qs = 0; qs < 2; qs++) {
    const unsigned short* qp =
        q + ((size_t)(b * 2048 + qbase + qs * 16 + lq)) * 2560 + h * 128 + grp * 8;
#pragma unroll
    for (int c = 0; c < 4; c++) qf[qs][c] = *(const short8*)(qp + c * 32);
  }

  f32x4 o[2][8] = {};
  float lsum[2] = {0.f, 0.f};
  const float C = 20.0f;

  const int kvperm = (lq >> 2) * 8 + (lq & 3);
  const unsigned short* kB = kv + (size_t)b * 2048 * 1024 + g * 128 + grp * 8;
  const unsigned short* vB =
      vt + ((size_t)((b * 4 + g) * 128 + lq)) * 2048 + grp * 8;
  const int fbase = wave * 8;
  unsigned short* dstb = &KV[0][fbase][0] + lane * 8;

  auto stage = [&](int bn, int kv0) {
    unsigned short* dst = dstb + bn * 16384;
    if (fbase < 16) {
#pragma unroll
      for (int j = 0; j < 8; j++) {
        int f = fbase + j, t = f >> 2, c = f & 3;
        const unsigned short* src =
            kB + (size_t)(kv0 + (t >> 1) * 32 + (t & 1) * 4 + kvperm) * 1024 + c * 32;
        async16(src, dst + j * 512);
      }
    } else {
#pragma unroll
      for (int j = 0; j < 8; j++) {
        int f = fbase - 16 + j, d0 = f >> 1, u = f & 1;
        const unsigned short* src = vB + (size_t)(d0 * 16) * 2048 + kv0 + u * 32;
        async16(src, dst + j * 512);
      }
    }
  };

  stage(0, 0);
  int buf = 0;
  for (int it = 0; it < 32; ++it) {
    __syncthreads();
    if (it < 31) stage(buf ^ 1, (it + 1) * 64);
    const unsigned short* Kb = &KV[buf][0][0] + lane * 8;

    f32x4 s[2][4] = {};
    __builtin_amdgcn_s_setprio(1);
#pragma unroll
    for (int c = 0; c < 4; c++) {
      short8 kf0 = *(const short8*)(Kb + (0 + c) * 512);
      short8 kf1 = *(const short8*)(Kb + (4 + c) * 512);
      short8 kf2 = *(const short8*)(Kb + (8 + c) * 512);
      short8 kf3 = *(const short8*)(Kb + (12 + c) * 512);
#pragma unroll
      for (int qs = 0; qs < 2; qs++) {
        s[qs][0] = mfma16(kf0, qf[qs][c], s[qs][0]);
        s[qs][1] = mfma16(kf1, qf[qs][c], s[qs][1]);
        s[qs][2] = mfma16(kf2, qf[qs][c], s[qs][2]);
        s[qs][3] = mfma16(kf3, qf[qs][c], s[qs][3]);
      }
    }
    __builtin_amdgcn_s_setprio(0);

    short8 pf[2][2];
#pragma unroll
    for (int qs = 0; qs < 2; qs++) {
      float ps = 0.f;
      union { short8 v; unsigned w[4]; } pk0, pk1;
#pragma unroll
      for (int t = 0; t < 4; t++) {
        float e0 = ex2(s[qs][t][0] - C);
        float e1 = ex2(s[qs][t][1] - C);
        float e2 = ex2(s[qs][t][2] - C);
        float e3 = ex2(s[qs][t][3] - C);
        ps += (e0 + e1) + (e2 + e3);
        unsigned w0 = cvtpk(e0, e1), w1 = cvtpk(e2, e3);
        if (t == 0) { pk0.w[0] = w0; pk0.w[1] = w1; }
        else if (t == 1) { pk0.w[2] = w0; pk0.w[3] = w1; }
        else if (t == 2) { pk1.w[0] = w0; pk1.w[1] = w1; }
        else { pk1.w[2] = w0; pk1.w[3] = w1; }
      }
      lsum[qs] += ps;
      pf[qs][0] = pk0.v;
      pf[qs][1] = pk1.v;
    }

    const unsigned short* Vb = Kb + 16 * 512;
    __builtin_amdgcn_s_setprio(1);
#pragma unroll
    for (int d0 = 0; d0 < 8; d0++) {
      short8 v0 = *(const short8*)(Vb + (d0 * 2 + 0) * 512);
      short8 v1 = *(const short8*)(Vb + (d0 * 2 + 1) * 512);
#pragma unroll
      for (int qs = 0; qs < 2; qs++) {
        o[qs][d0] = mfma16(pf[qs][0], v0, o[qs][d0]);
        o[qs][d0] = mfma16(pf[qs][1], v1, o[qs][d0]);
      }
    }
    __builtin_amdgcn_s_setprio(0);
    buf ^= 1;
  }

  unsigned short* cp = ctx + ((size_t)(b * 2048 + qbase)) * 2048 + h * 128;
#pragma unroll
  for (int qs = 0; qs < 2; qs++) {
    float l = lsum[qs];
    l += __shfl_xor(l, 16);
    l += __shfl_xor(l, 32);
    float ri = 1.0f / l;
    float r0 = __shfl(ri, grp * 4 + 0), r1 = __shfl(ri, grp * 4 + 1);
    float r2 = __shfl(ri, grp * 4 + 2), r3 = __shfl(ri, grp * 4 + 3);
#pragma unroll
    for (int d0 = 0; d0 < 8; d0++) {
      int col = d0 * 16 + lq;
      cp[(size_t)(qs * 16 + grp * 4 + 0) * 2048 + col] = f2b(o[qs][d0][0] * r0);
      cp[(size_t)(qs * 16 + grp * 4 + 1) * 2048 + col] = f2b(o[qs][d0][1] * r1);
      cp[(size_t)(qs * 16 + grp * 4 + 2) * 2048 + col] = f2b(o[qs][d0][2] * r2);
      cp[(size_t)(qs * 16 + grp * 4 + 3) * 2048 + col] = f2b(o[qs][d0][3] * r3);
    }
  }
}

// ---------------- host ----------------
extern "C" void kernel_launch(void* const* d_in, const int* in_sizes, int n_in,
                              void* d_out, int out_size, void* d_ws, size_t ws_size,
                              hipStream_t stream) {
  const float* h  = (const float*)d_in[0];
  const float* Wq = (const float*)d_in[1];
  const float* bq = (const float*)d_in[2];
  const float* Wl = (const float*)d_in[3];
  const float* bl = (const float*)d_in[4];
  const float* Wk = (const float*)d_in[5];
  const float* bk = (const float*)d_in[6];
  const float* Wv = (const float*)d_in[7];
  const float* bv = (const float*)d_in[8];
  const float* Wo = (const float*)d_in[9];
  const float* bo = (const float*)d_in[10];
  float* out = (float*)d_out;

  const int M = 4096;  // B*S

  char* w = (char*)d_ws;
  auto take = [&](size_t elems) {
    void* p = (void*)w;
    w += (elems * 2 + 255) & ~(size_t)255;
    return (unsigned short*)p;
  };
  unsigned short* hb   = take(8388608);   // [4096][2048]
  unsigned short* WqlT = take(5242880);   // [2560][2048]
  unsigned short* WkvT = take(524288);    // [1024][512]
  unsigned short* WoT  = take(4194304);   // [2048][2048]
  unsigned short* qlat = take(10485760);  // [4096][2560]
  unsigned short* kvb  = take(4194304);   // [4096][1024]
  unsigned short* vtb  = take(2097152);   // [2*512][2048]
  unsigned short* ctx  = take(8388608);   // [4096][2048]
  float* bql = (float*)take(2560);
  float* bkv = (float*)take(1024);

  const float scale = 0.08838834764831845f * 1.4426950408889634f;

  mega_prep<<<13825, 256, 0, stream>>>(h, hb, Wq, Wl, Wk, Wv, Wo,
                                       WqlT, WkvT, WoT,
                                       bq, bl, bk, bv, bql, bkv, scale);

  gemm_8ph<0><<<dim3(10, 16), 512, 0, stream>>>(hb, WqlT, bql, qlat, M, 2560, 2048, 1.0f);
  gemm_bt<0><<<dim3(8, 32), 256, 0, stream>>>(qlat + 2048, WkvT, bkv, kvb, M, 1024, 512, 2560, 1.0f);

  transpose_v<<<dim3(16, 64, 2), 256, 0, stream>>>(kvb, vtb);

  attn_kernel<<<512, 256, 0, stream>>>(qlat, kvb, vtb, ctx);

  gemm_8ph<1><<<dim3(8, 16), 512, 0, stream>>>(ctx, WoT, bo, out, M, 2048, 2048, 1.0f);
}

// Round 16
// 237.269 us; speedup vs baseline: 1.1500x; 1.0171x over previous
//
#include <hip/hip_runtime.h>
#include <stdint.h>

// GroupedQueryLatentAttention on MI355X (gfx950).
// B=2 S=2048 HID=2048 HEADS=16 D=128 GROUPS=4 LATENT=512 KV=512.
// R16 = R13/R15 pipeline with transpose_v FUSED into the kv projection:
// gemm_kv writes K cols to kvb (attn K source) and V cols directly in
// transposed layout to vtb (one ushort4 store per fragment: acc rows r=0..3
// are consecutive s). Bits identical to the old transpose_v output.
// Pipeline: mega_prep -> gemm_8ph (q+latent merged, 256x256x64 4-phase,
// frag-packed LDS, counted vmcnt, XCD swizzle) -> gemm_kv -> attn (KVBLK=64,
// fixed-offset exp2 softmax, cvt_pk, XCD-pinned KV) -> gemm_8ph o-proj.

#define DEV static __device__ __forceinline__

using short8  = __attribute__((ext_vector_type(8))) short;
using f32x4   = __attribute__((ext_vector_type(4))) float;
using ushort4v = __attribute__((ext_vector_type(4))) unsigned short;

typedef __attribute__((address_space(1))) void gvoid;
typedef __attribute__((address_space(3))) void lvoid;

DEV unsigned short f2b(float f) {
  unsigned u = __builtin_bit_cast(unsigned, f);
  unsigned r = (u + 0x7fffu + ((u >> 16) & 1u)) >> 16;
  return (unsigned short)r;
}
DEV float b2f(unsigned short s) {
  unsigned u = ((unsigned)s) << 16;
  return __builtin_bit_cast(float, u);
}

DEV unsigned cvtpk(float lo, float hi) {
  unsigned r;
  asm("v_cvt_pk_bf16_f32 %0, %1, %2" : "=v"(r) : "v"(lo), "v"(hi));
  return r;
}

DEV float ex2(float x) { return __builtin_amdgcn_exp2f(x); }

// async global->LDS, 16B per lane. LDS dest resolves to firstlane base + lane*16.
DEV void async16(const void* g, void* l) {
  __builtin_amdgcn_global_load_lds((gvoid*)(uintptr_t)g,
                                   (lvoid*)(uint32_t)(uintptr_t)l, 16, 0, 0);
}

DEV f32x4 mfma16(short8 a, short8 b, f32x4 c) {
  return __builtin_amdgcn_mfma_f32_16x16x32_bf16(a, b, c, 0, 0, 0);
}

// ---------------- mega prep: cvt + all weight transposes + bias concat -----
__global__ __launch_bounds__(256) void mega_prep(
    const float* __restrict__ h, unsigned short* __restrict__ hb,
    const float* __restrict__ Wq, const float* __restrict__ Wl,
    const float* __restrict__ Wk, const float* __restrict__ Wv,
    const float* __restrict__ Wo,
    unsigned short* __restrict__ WqlT, unsigned short* __restrict__ WkvT,
    unsigned short* __restrict__ WoT,
    const float* __restrict__ bq, const float* __restrict__ bl,
    const float* __restrict__ bk, const float* __restrict__ bv,
    float* __restrict__ bql, float* __restrict__ bkv, float qscale) {
  __shared__ float tile[32][33];
  const int bid = blockIdx.x;
  const int tid = threadIdx.x;

  if (bid < 4096) {
    long i = ((long)bid * 256 + tid) * 8;
    float4 a = *(const float4*)(h + i);
    float4 b = *(const float4*)(h + i + 4);
    short8 o;
    o[0] = (short)f2b(a.x); o[1] = (short)f2b(a.y);
    o[2] = (short)f2b(a.z); o[3] = (short)f2b(a.w);
    o[4] = (short)f2b(b.x); o[5] = (short)f2b(b.y);
    o[6] = (short)f2b(b.z); o[7] = (short)f2b(b.w);
    *(short8*)(hb + i) = o;
    return;
  }

  const float* in; unsigned short* out; int R, C, bx, by; float sc = 1.0f;
  if (bid < 8192) {
    int l = bid - 4096; in = Wq; out = WqlT; R = 2048; C = 2048;
    bx = l & 63; by = l >> 6; sc = qscale;
  } else if (bid < 9216) {
    int l = bid - 8192; in = Wl; out = WqlT + 2048 * 2048; R = 2048; C = 512;
    bx = l & 15; by = l >> 4;
  } else if (bid < 9472) {
    int l = bid - 9216; in = Wk; out = WkvT; R = 512; C = 512;
    bx = l & 15; by = l >> 4;
  } else if (bid < 9728) {
    int l = bid - 9472; in = Wv; out = WkvT + 262144; R = 512; C = 512;
    bx = l & 15; by = l >> 4;
  } else if (bid < 13824) {
    int l = bid - 9728; in = Wo; out = WoT; R = 2048; C = 2048;
    bx = l & 63; by = l >> 6;
  } else {
    for (int t = tid; t < 2560; t += 256)
      bql[t] = (t < 2048) ? bq[t] * qscale : bl[t - 2048];
    for (int t = tid; t < 1024; t += 256)
      bkv[t] = (t < 512) ? bk[t] : bv[t - 512];
    return;
  }

  int bc = bx * 32, br = by * 32;
  int tx = tid & 31, ty0 = tid >> 5;
#pragma unroll
  for (int ty = ty0; ty < 32; ty += 8)
    tile[ty][tx] = in[(size_t)(br + ty) * C + bc + tx] * sc;
  __syncthreads();
#pragma unroll
  for (int ty = ty0; ty < 32; ty += 8)
    out[(size_t)(bc + ty) * R + br + tx] = f2b(tile[tx][ty]);
}

// ---------------- kv projection GEMM 128x128 with fused V-transpose --------
// C[M=4096, N=1024] = lat (qlat cols 2048.., lda 2560) x WkvT^T + bkv.
// Cols 0..511 (K) -> kvb[row*1024 + col]; cols 512.. (V) -> vtb transposed:
// vtb[(b*512 + (col-512))*2048 + s], b=row>>11, s=row&2047. acc rows r=0..3
// are consecutive s -> single ushort4 (8B) store per (m,n) fragment.
__global__ __launch_bounds__(256) void gemm_kv(
    const unsigned short* __restrict__ A,   // lat, row stride 2560
    const unsigned short* __restrict__ Bt,  // WkvT [1024][512]
    const float* __restrict__ bias,         // bkv [1024]
    unsigned short* __restrict__ kvb,       // [4096][1024], K half written
    unsigned short* __restrict__ vtb) {     // [2*512][2048]
  const int K = 512, lda = 2560;
  __shared__ unsigned short As[128 * 32];
  __shared__ unsigned short Bs[128 * 32];
  int tid = threadIdx.x;
  int lane = tid & 63, wave = tid >> 6;
  int wr = wave >> 1, wc = wave & 1;
  int lq = lane & 15, grp = lane >> 4;
  int brow = blockIdx.y * 128, bcol = blockIdx.x * 128;

  f32x4 acc[4][4] = {};

  for (int k0 = 0; k0 < K; k0 += 32) {
    {
      int e0 = tid * 8;
      int r0 = e0 >> 5, c0 = e0 & 31;
      async16(A + (size_t)(brow + r0) * lda + k0 + c0, As + e0);
      async16(Bt + (size_t)(bcol + r0) * K + k0 + c0, Bs + e0);
      int e1 = (256 + tid) * 8;
      int r1 = e1 >> 5, c1 = e1 & 31;
      async16(A + (size_t)(brow + r1) * lda + k0 + c1, As + e1);
      async16(Bt + (size_t)(bcol + r1) * K + k0 + c1, Bs + e1);
    }
    __syncthreads();

    short8 af[4], bf[4];
#pragma unroll
    for (int m = 0; m < 4; m++)
      af[m] = *(const short8*)(As + (wr * 64 + m * 16 + lq) * 32 + grp * 8);
#pragma unroll
    for (int n = 0; n < 4; n++)
      bf[n] = *(const short8*)(Bs + (wc * 64 + n * 16 + lq) * 32 + grp * 8);
#pragma unroll
    for (int m = 0; m < 4; m++)
#pragma unroll
      for (int n = 0; n < 4; n++)
        acc[m][n] = mfma16(af[m], bf[n], acc[m][n]);
    __syncthreads();
  }

#pragma unroll
  for (int n = 0; n < 4; n++) {
    int col = bcol + wc * 64 + n * 16 + lq;
    float bv = bias[col];
    if (col < 512) {  // K half: normal row-major store
#pragma unroll
      for (int m = 0; m < 4; m++) {
#pragma unroll
        for (int r = 0; r < 4; r++) {
          int row = brow + wr * 64 + m * 16 + grp * 4 + r;
          kvb[(size_t)row * 1024 + col] = f2b(acc[m][n][r] + bv);
        }
      }
    } else {  // V half: transposed store, 4 consecutive s per fragment
      int vc = col - 512;
#pragma unroll
      for (int m = 0; m < 4; m++) {
        int row0 = brow + wr * 64 + m * 16 + grp * 4;
        int b = row0 >> 11, s0 = row0 & 2047;
        ushort4v pk;
        pk[0] = f2b(acc[m][n][0] + bv);
        pk[1] = f2b(acc[m][n][1] + bv);
        pk[2] = f2b(acc[m][n][2] + bv);
        pk[3] = f2b(acc[m][n][3] + bv);
        *(ushort4v*)(vtb + ((size_t)(b * 512 + vc)) * 2048 + s0) = pk;
      }
    }
  }
}

// ---------------- GEMM 256x256x64, 8 waves, 4-phase pipelined --------------
template <int OUT_F32>
__global__ __launch_bounds__(512, 1) void gemm_8ph(
    const unsigned short* __restrict__ A, const unsigned short* __restrict__ Bt,
    const float* __restrict__ bias, void* __restrict__ Cout,
    int M, int N, int K, float scale) {
  __shared__ __align__(1024) unsigned short L[2][32768];  // 2 x 64KB
  const int tid = threadIdx.x, lane = tid & 63, wave = tid >> 6;
  const int lq = lane & 15, grp = lane >> 4;
  const int wr = wave >> 2, wc = wave & 3;

  const int gx = gridDim.x;
  int nwg = gx * gridDim.y;
  int bid = blockIdx.y * gx + blockIdx.x;
  int wgid = (bid & 7) * (nwg >> 3) + (bid >> 3);
  int bx = wgid % gx, by = wgid / gx;
  const int brow = by * 256, bcol = bx * 256;

  const unsigned short* srcA[2];
  const unsigned short* srcB[2];
  unsigned short* dstA[2];
  unsigned short* dstB[2];
#pragma unroll
  for (int j = 0; j < 2; j++) {
    int f = wave + j * 8, kk = f & 1, fi = f >> 1;
    int awr = fi >> 2, aml = fi & 3;
    srcA[j] = A + (size_t)(brow + (awr * 8 + aml) * 16 + lq) * K + kk * 32 + grp * 8;
    dstA[j] = &L[0][0] + f * 512 + lane * 8;
    int bwc = fi >> 1, bnl = fi & 1;
    srcB[j] = Bt + (size_t)(bcol + (bwc * 4 + bnl) * 16 + lq) * K + kk * 32 + grp * 8;
    dstB[j] = &L[0][0] + 16384 + f * 512 + lane * 8;
  }
  auto stgA = [&](int p, int mh, int k0) {
#pragma unroll
    for (int j = 0; j < 2; j++)
      async16(srcA[j] + (size_t)mh * 64 * K + k0, dstA[j] + p * 32768 + mh * 8192);
  };
  auto stgB = [&](int p, int nh, int k0) {
#pragma unroll
    for (int j = 0; j < 2; j++)
      async16(srcB[j] + (size_t)nh * 32 * K + k0, dstB[j] + p * 32768 + nh * 8192);
  };
  auto ldAf = [&](int p, int mh, int ml, int kk) -> short8 {
    return *(const short8*)(&L[0][0] + p * 32768 + mh * 8192 +
                            ((wr * 4 + ml) * 2 + kk) * 512 + lane * 8);
  };
  auto ldBf = [&](int p, int nh, int nl, int kk) -> short8 {
    return *(const short8*)(&L[0][0] + p * 32768 + 16384 + nh * 8192 +
                            ((wc * 2 + nl) * 2 + kk) * 512 + lane * 8);
  };

  f32x4 acc[8][4] = {};
  short8 af[4][2], bf0[2][2], bf1[2][2];
  const int NT = K >> 6;

  stgA(0, 0, 0); stgB(0, 0, 0); stgB(0, 1, 0); stgA(0, 1, 0);
  asm volatile("s_waitcnt vmcnt(4)" ::: "memory");  // AH0,BH0 landed
  __builtin_amdgcn_s_barrier();

  for (int T = 0; T < NT; ++T) {
    const int cur = T & 1, nxt = cur ^ 1;
    const bool pf = (T + 1 < NT);
    const int k1 = (T + 1) << 6;

    // ---- q0: AH0+BH0 reads, stage AH0(T+1), acc[0..3][0..1] ----
#pragma unroll
    for (int ml = 0; ml < 4; ml++) {
      af[ml][0] = ldAf(cur, 0, ml, 0);
      af[ml][1] = ldAf(cur, 0, ml, 1);
    }
#pragma unroll
    for (int nl = 0; nl < 2; nl++) {
      bf0[nl][0] = ldBf(cur, 0, nl, 0);
      bf0[nl][1] = ldBf(cur, 0, nl, 1);
    }
    if (pf) stgA(nxt, 0, k1);
    __builtin_amdgcn_s_setprio(1);
#pragma unroll
    for (int ml = 0; ml < 4; ml++)
#pragma unroll
      for (int nl = 0; nl < 2; nl++) {
        acc[ml][nl] = mfma16(af[ml][0], bf0[nl][0], acc[ml][nl]);
        acc[ml][nl] = mfma16(af[ml][1], bf0[nl][1], acc[ml][nl]);
      }
    __builtin_amdgcn_s_setprio(0);
    if (pf) asm volatile("s_waitcnt vmcnt(4)" ::: "memory");  // BH1(T) landed
    else    asm volatile("s_waitcnt vmcnt(2)" ::: "memory");
    __builtin_amdgcn_s_barrier();

    // ---- q1: BH1 reads, stage BH0(T+1), acc[0..3][2..3] ----
#pragma unroll
    for (int nl = 0; nl < 2; nl++) {
      bf1[nl][0] = ldBf(cur, 1, nl, 0);
      bf1[nl][1] = ldBf(cur, 1, nl, 1);
    }
    if (pf) stgB(nxt, 0, k1);
    __builtin_amdgcn_s_setprio(1);
#pragma unroll
    for (int ml = 0; ml < 4; ml++)
#pragma unroll
      for (int nl = 0; nl < 2; nl++) {
        acc[ml][2 + nl] = mfma16(af[ml][0], bf1[nl][0], acc[ml][2 + nl]);
        acc[ml][2 + nl] = mfma16(af[ml][1], bf1[nl][1], acc[ml][2 + nl]);
      }
    __builtin_amdgcn_s_setprio(0);
    if (pf) asm volatile("s_waitcnt vmcnt(4)" ::: "memory");  // AH1(T) landed
    else    asm volatile("s_waitcnt vmcnt(0)" ::: "memory");
    __builtin_amdgcn_s_barrier();

    // ---- q2: AH1 reads, stage BH1(T+1), acc[4..7][0..1] ----
#pragma unroll
    for (int ml = 0; ml < 4; ml++) {
      af[ml][0] = ldAf(cur, 1, ml, 0);
      af[ml][1] = ldAf(cur, 1, ml, 1);
    }
    if (pf) stgB(nxt, 1, k1);
    __builtin_amdgcn_s_setprio(1);
#pragma unroll
    for (int ml = 0; ml < 4; ml++)
#pragma unroll
      for (int nl = 0; nl < 2; nl++) {
        acc[4 + ml][nl] = mfma16(af[ml][0], bf0[nl][0], acc[4 + ml][nl]);
        acc[4 + ml][nl] = mfma16(af[ml][1], bf0[nl][1], acc[4 + ml][nl]);
      }
    __builtin_amdgcn_s_setprio(0);
    __builtin_amdgcn_s_barrier();  // q3 reads nothing from LDS

    // ---- q3: stage AH1(T+1), acc[4..7][2..3] ----
    if (pf) stgA(nxt, 1, k1);
    __builtin_amdgcn_s_setprio(1);
#pragma unroll
    for (int ml = 0; ml < 4; ml++)
#pragma unroll
      for (int nl = 0; nl < 2; nl++) {
        acc[4 + ml][2 + nl] = mfma16(af[ml][0], bf1[nl][0], acc[4 + ml][2 + nl]);
        acc[4 + ml][2 + nl] = mfma16(af[ml][1], bf1[nl][1], acc[4 + ml][2 + nl]);
      }
    __builtin_amdgcn_s_setprio(0);
    if (pf) asm volatile("s_waitcnt vmcnt(4)" ::: "memory");  // AH0,BH0(T+1) landed
    __builtin_amdgcn_s_barrier();
  }

#pragma unroll
  for (int mh = 0; mh < 2; mh++)
#pragma unroll
    for (int ml = 0; ml < 4; ml++)
#pragma unroll
      for (int nh = 0; nh < 2; nh++)
#pragma unroll
        for (int nl = 0; nl < 2; nl++) {
          int col = bcol + wc * 64 + (nh * 2 + nl) * 16 + lq;
          float bv = bias[col];
          f32x4 a = acc[mh * 4 + ml][nh * 2 + nl];
#pragma unroll
          for (int r = 0; r < 4; r++) {
            int row = brow + wr * 128 + (mh * 4 + ml) * 16 + grp * 4 + r;
            float v = (a[r] + bv) * scale;
            if (OUT_F32)
              ((float*)Cout)[(size_t)row * N + col] = v;
            else
              ((unsigned short*)Cout)[(size_t)row * N + col] = f2b(v);
          }
        }
}

// ---------------- flash attention (R11, q row stride 2560) ----------------
__global__ __launch_bounds__(256, 2) void attn_kernel(
    const unsigned short* __restrict__ q,   // qlat [B*S][2560], cols 0..2047 = q
    const unsigned short* __restrict__ kv,  // [B*S][1024]; K = cols 0..511
    const unsigned short* __restrict__ vt,  // [(b*4+g)*128 + d][2048]
    unsigned short* __restrict__ ctx) {     // [B*S][2048]
  __shared__ unsigned short KV[2][32][512];
  const int lane = threadIdx.x & 63, wave = threadIdx.x >> 6;
  const int lq = lane & 15, grp = lane >> 4;
  const int bid = blockIdx.x;
  const int combo = bid & 7;
  const int slot = bid >> 3;
  const int b = combo >> 2, g = combo & 3;
  const int h = g * 4 + (slot >> 4);
  const int qbase = (slot & 15) * 128 + wave * 32;

  short8 qf[2][4];
#pragma unroll
  for (int qs = 0; qs < 2; qs++) {
    const unsigned short* qp =
        q + ((size_t)(b * 2048 + qbase + qs * 16 + lq)) * 2560 + h * 128 + grp * 8;
#pragma unroll
    for (int c = 0; c < 4; c++) qf[qs][c] = *(const short8*)(qp + c * 32);
  }

  f32x4 o[2][8] = {};
  float lsum[2] = {0.f, 0.f};
  const float C = 20.0f;

  const int kvperm = (lq >> 2) * 8 + (lq & 3);
  const unsigned short* kB = kv + (size_t)b * 2048 * 1024 + g * 128 + grp * 8;
  const unsigned short* vB =
      vt + ((size_t)((b * 4 + g) * 128 + lq)) * 2048 + grp * 8;
  const int fbase = wave * 8;
  unsigned short* dstb = &KV[0][fbase][0] + lane * 8;

  auto stage = [&](int bn, int kv0) {
    unsigned short* dst = dstb + bn * 16384;
    if (fbase < 16) {
#pragma unroll
      for (int j = 0; j < 8; j++) {
        int f = fbase + j, t = f >> 2, c = f & 3;
        const unsigned short* src =
            kB + (size_t)(kv0 + (t >> 1) * 32 + (t & 1) * 4 + kvperm) * 1024 + c * 32;
        async16(src, dst + j * 512);
      }
    } else {
#pragma unroll
      for (int j = 0; j < 8; j++) {
        int f = fbase - 16 + j, d0 = f >> 1, u = f & 1;
        const unsigned short* src = vB + (size_t)(d0 * 16) * 2048 + kv0 + u * 32;
        async16(src, dst + j * 512);
      }
    }
  };

  stage(0, 0);
  int buf = 0;
  for (int it = 0; it < 32; ++it) {
    __syncthreads();
    if (it < 31) stage(buf ^ 1, (it + 1) * 64);
    const unsigned short* Kb = &KV[buf][0][0] + lane * 8;

    f32x4 s[2][4] = {};
    __builtin_amdgcn_s_setprio(1);
#pragma unroll
    for (int c = 0; c < 4; c++) {
      short8 kf0 = *(const short8*)(Kb + (0 + c) * 512);
      short8 kf1 = *(const short8*)(Kb + (4 + c) * 512);
      short8 kf2 = *(const short8*)(Kb + (8 + c) * 512);
      short8 kf3 = *(const short8*)(Kb + (12 + c) * 512);
#pragma unroll
      for (int qs = 0; qs < 2; qs++) {
        s[qs][0] = mfma16(kf0, qf[qs][c], s[qs][0]);
        s[qs][1] = mfma16(kf1, qf[qs][c], s[qs][1]);
        s[qs][2] = mfma16(kf2, qf[qs][c], s[qs][2]);
        s[qs][3] = mfma16(kf3, qf[qs][c], s[qs][3]);
      }
    }
    __builtin_amdgcn_s_setprio(0);

    short8 pf[2][2];
#pragma unroll
    for (int qs = 0; qs < 2; qs++) {
      float ps = 0.f;
      union { short8 v; unsigned w[4]; } pk0, pk1;
#pragma unroll
      for (int t = 0; t < 4; t++) {
        float e0 = ex2(s[qs][t][0] - C);
        float e1 = ex2(s[qs][t][1] - C);
        float e2 = ex2(s[qs][t][2] - C);
        float e3 = ex2(s[qs][t][3] - C);
        ps += (e0 + e1) + (e2 + e3);
        unsigned w0 = cvtpk(e0, e1), w1 = cvtpk(e2, e3);
        if (t == 0) { pk0.w[0] = w0; pk0.w[1] = w1; }
        else if (t == 1) { pk0.w[2] = w0; pk0.w[3] = w1; }
        else if (t == 2) { pk1.w[0] = w0; pk1.w[1] = w1; }
        else { pk1.w[2] = w0; pk1.w[3] = w1; }
      }
      lsum[qs] += ps;
      pf[qs][0] = pk0.v;
      pf[qs][1] = pk1.v;
    }

    const unsigned short* Vb = Kb + 16 * 512;
    __builtin_amdgcn_s_setprio(1);
#pragma unroll
    for (int d0 = 0; d0 < 8; d0++) {
      short8 v0 = *(const short8*)(Vb + (d0 * 2 + 0) * 512);
      short8 v1 = *(const short8*)(Vb + (d0 * 2 + 1) * 512);
#pragma unroll
      for (int qs = 0; qs < 2; qs++) {
        o[qs][d0] = mfma16(pf[qs][0], v0, o[qs][d0]);
        o[qs][d0] = mfma16(pf[qs][1], v1, o[qs][d0]);
      }
    }
    __builtin_amdgcn_s_setprio(0);
    buf ^= 1;
  }

  unsigned short* cp = ctx + ((size_t)(b * 2048 + qbase)) * 2048 + h * 128;
#pragma unroll
  for (int qs = 0; qs < 2; qs++) {
    float l = lsum[qs];
    l += __shfl_xor(l, 16);
    l += __shfl_xor(l, 32);
    float ri = 1.0f / l;
    float r0 = __shfl(ri, grp * 4 + 0), r1 = __shfl(ri, grp * 4 + 1);
    float r2 = __shfl(ri, grp * 4 + 2), r3 = __shfl(ri, grp * 4 + 3);
#pragma unroll
    for (int d0 = 0; d0 < 8; d0++) {
      int col = d0 * 16 + lq;
      cp[(size_t)(qs * 16 + grp * 4 + 0) * 2048 + col] = f2b(o[qs][d0][0] * r0);
      cp[(size_t)(qs * 16 + grp * 4 + 1) * 2048 + col] = f2b(o[qs][d0][1] * r1);
      cp[(size_t)(qs * 16 + grp * 4 + 2) * 2048 + col] = f2b(o[qs][d0][2] * r2);
      cp[(size_t)(qs * 16 + grp * 4 + 3) * 2048 + col] = f2b(o[qs][d0][3] * r3);
    }
  }
}

// ---------------- host ----------------
extern "C" void kernel_launch(void* const* d_in, const int* in_sizes, int n_in,
                              void* d_out, int out_size, void* d_ws, size_t ws_size,
                              hipStream_t stream) {
  const float* h  = (const float*)d_in[0];
  const float* Wq = (const float*)d_in[1];
  const float* bq = (const float*)d_in[2];
  const float* Wl = (const float*)d_in[3];
  const float* bl = (const float*)d_in[4];
  const float* Wk = (const float*)d_in[5];
  const float* bk = (const float*)d_in[6];
  const float* Wv = (const float*)d_in[7];
  const float* bv = (const float*)d_in[8];
  const float* Wo = (const float*)d_in[9];
  const float* bo = (const float*)d_in[10];
  float* out = (float*)d_out;

  const int M = 4096;  // B*S

  char* w = (char*)d_ws;
  auto take = [&](size_t elems) {
    void* p = (void*)w;
    w += (elems * 2 + 255) & ~(size_t)255;
    return (unsigned short*)p;
  };
  unsigned short* hb   = take(8388608);   // [4096][2048]
  unsigned short* WqlT = take(5242880);   // [2560][2048]
  unsigned short* WkvT = take(524288);    // [1024][512]
  unsigned short* WoT  = take(4194304);   // [2048][2048]
  unsigned short* qlat = take(10485760);  // [4096][2560]
  unsigned short* kvb  = take(4194304);   // [4096][1024] (K half used)
  unsigned short* vtb  = take(2097152);   // [2*512][2048]
  unsigned short* ctx  = take(8388608);   // [4096][2048]
  float* bql = (float*)take(2560);
  float* bkv = (float*)take(1024);

  const float scale = 0.08838834764831845f * 1.4426950408889634f;

  mega_prep<<<13825, 256, 0, stream>>>(h, hb, Wq, Wl, Wk, Wv, Wo,
                                       WqlT, WkvT, WoT,
                                       bq, bl, bk, bv, bql, bkv, scale);

  gemm_8ph<0><<<dim3(10, 16), 512, 0, stream>>>(hb, WqlT, bql, qlat, M, 2560, 2048, 1.0f);
  gemm_kv<<<dim3(8, 32), 256, 0, stream>>>(qlat + 2048, WkvT, bkv, kvb, vtb);

  attn_kernel<<<512, 256, 0, stream>>>(qlat, kvb, vtb, ctx);

  gemm_8ph<1><<<dim3(8, 16), 512, 0, stream>>>(ctx, WoT, bo, out, M, 2048, 2048, 1.0f);
}